// Round 1
// baseline (268.399 us; speedup 1.0000x reference)
//
#include <hip/hip_runtime.h>

#define T_DIM 4096
#define J_DIM 24
#define NCI 16
#define NCO 16
#define G_DIM 75
#define TILE_T 1024

// Inverse of ALL_IDX: for each original joint j, the output g-positions that
// replicate it. Derived from TOPOLOGY/NEIGHBOR_DIST/EE_ID in the reference
// (nl[0] patched to include EE joints). Counts sum to 75.
__device__ const int d_nrep[J_DIM] = {4,3,3,3,3,3,3,3,3,5,3,3,3,3,3,3,3,3,3,3,3,3,3,3};
__device__ const int d_repl[J_DIM][5] = {
  {0, 9, 12, 15, -1},
  {1, 10, 18, -1, -1},
  {2, 13, 21, -1, -1},
  {3, 16, 24, -1, -1},
  {11, 19, 27, -1, -1},
  {14, 22, 30, -1, -1},
  {17, 25, 33, -1, -1},
  {20, 28, 38, -1, -1},
  {23, 31, 40, -1, -1},
  {26, 34, 42, 45, 48},
  {4, 29, 39, -1, -1},
  {5, 32, 41, -1, -1},
  {35, 43, 51, -1, -1},
  {36, 46, 53, -1, -1},
  {37, 49, 56, -1, -1},
  {6, 44, 52, -1, -1},
  {47, 54, 59, -1, -1},
  {50, 57, 62, -1, -1},
  {55, 60, 65, -1, -1},
  {58, 63, 68, -1, -1},
  {61, 66, 71, -1, -1},
  {64, 69, 73, -1, -1},
  {7, 67, 72, -1, -1},
  {8, 70, 74, -1, -1},
};

__global__ __launch_bounds__(256) void skel_conv(
    const float* __restrict__ x, const float* __restrict__ W,
    const float* __restrict__ bias, float* __restrict__ out) {
  const int tile = blockIdx.x;   // t-tile
  const int j    = blockIdx.y;   // original joint
  const int b    = blockIdx.z;   // batch
  const int tid  = (int)threadIdx.x;
  const int lane = tid & 63;
  const int t0   = tile * TILE_T + tid * 4;

  // Stage W as float4 {w0,w1,w2,0} and bias in LDS (broadcast reads later).
  __shared__ float4 Wl[NCI][NCO];
  __shared__ float  bl[NCO];
  {
    const int co = tid & 15, ci = tid >> 4;  // 256 threads cover 16x16 exactly
    const float* wp = W + (co * NCI + ci) * 3;
    Wl[ci][co] = make_float4(wp[0], wp[1], wp[2], 0.f);
    if (tid < NCO) bl[tid] = bias[tid];
  }
  __syncthreads();

  float4 acc[NCO];
#pragma unroll
  for (int co = 0; co < NCO; ++co) acc[co] = make_float4(0.f, 0.f, 0.f, 0.f);

#pragma unroll 4
  for (int ci = 0; ci < NCI; ++ci) {
    const float* xp = x + (((size_t)b * NCI + ci) * J_DIM + j) * T_DIM;
    const float4 v = *(const float4*)(xp + t0);
    // halo via in-wave shuffle; wave-edge lanes patch with a direct load
    float xm1 = __shfl_up(v.w, 1);
    float xp4 = __shfl_down(v.x, 1);
    if (lane == 0)  xm1 = (t0 > 0) ? xp[t0 - 1] : 0.f;
    if (lane == 63) xp4 = (t0 + 4 < T_DIM) ? xp[t0 + 4] : 0.f;
#pragma unroll
    for (int co = 0; co < NCO; ++co) {
      const float4 w = Wl[ci][co];
      acc[co].x = fmaf(xm1, w.x, fmaf(v.x, w.y, fmaf(v.y, w.z, acc[co].x)));
      acc[co].y = fmaf(v.x, w.x, fmaf(v.y, w.y, fmaf(v.z, w.z, acc[co].y)));
      acc[co].z = fmaf(v.y, w.x, fmaf(v.z, w.y, fmaf(v.w, w.z, acc[co].z)));
      acc[co].w = fmaf(v.z, w.x, fmaf(v.w, w.y, fmaf(xp4, w.z, acc[co].w)));
    }
  }

  // bias once, before replication
#pragma unroll
  for (int co = 0; co < NCO; ++co) {
    const float bb = bl[co];
    acc[co].x += bb; acc[co].y += bb; acc[co].z += bb; acc[co].w += bb;
  }

  // replicate conv result to all gather positions of joint j
  const int nrep = d_nrep[j];
  for (int r = 0; r < nrep; ++r) {
    const int g = d_repl[j][r];
    float* op = out + ((size_t)b * NCO * G_DIM + g) * T_DIM + t0;
#pragma unroll
    for (int co = 0; co < NCO; ++co) {
      *(float4*)(op + (size_t)co * (G_DIM * T_DIM)) = acc[co];
    }
  }
}

extern "C" void kernel_launch(void* const* d_in, const int* in_sizes, int n_in,
                              void* d_out, int out_size, void* d_ws, size_t ws_size,
                              hipStream_t stream) {
  const float* x    = (const float*)d_in[0];
  const float* W    = (const float*)d_in[1];
  const float* bias = (const float*)d_in[2];
  float* out = (float*)d_out;

  dim3 grid(T_DIM / TILE_T, J_DIM, 32);
  dim3 block(256);
  skel_conv<<<grid, block, 0, stream>>>(x, W, bias, out);
}

// Round 2
// 198.747 us; speedup vs baseline: 1.3505x; 1.3505x over previous
//
#include <hip/hip_runtime.h>

#define T_DIM 4096
#define J_DIM 24
#define NCI 16
#define NCO 16
#define G_DIM 75
#define TILE_T 256   // t-elements per block (64 lanes x 4)

// Inverse of ALL_IDX: for each original joint j, the output g-positions that
// replicate it (conv kernel height is 1, so gathered rows are pure copies).
__device__ const int d_nrep[J_DIM] = {4,3,3,3,3,3,3,3,3,5,3,3,3,3,3,3,3,3,3,3,3,3,3,3};
__device__ const int d_repl[J_DIM][5] = {
  {0, 9, 12, 15, -1},
  {1, 10, 18, -1, -1},
  {2, 13, 21, -1, -1},
  {3, 16, 24, -1, -1},
  {11, 19, 27, -1, -1},
  {14, 22, 30, -1, -1},
  {17, 25, 33, -1, -1},
  {20, 28, 38, -1, -1},
  {23, 31, 40, -1, -1},
  {26, 34, 42, 45, 48},
  {4, 29, 39, -1, -1},
  {5, 32, 41, -1, -1},
  {35, 43, 51, -1, -1},
  {36, 46, 53, -1, -1},
  {37, 49, 56, -1, -1},
  {6, 44, 52, -1, -1},
  {47, 54, 59, -1, -1},
  {50, 57, 62, -1, -1},
  {55, 60, 65, -1, -1},
  {58, 63, 68, -1, -1},
  {61, 66, 71, -1, -1},
  {64, 69, 73, -1, -1},
  {7, 67, 72, -1, -1},
  {8, 70, 74, -1, -1},
};

__global__ __launch_bounds__(256, 8) void skel_conv(
    const float* __restrict__ x, const float* __restrict__ W,
    const float* __restrict__ bias, float* __restrict__ out) {
  const int tile = blockIdx.x;   // t-tile (16 tiles of 256)
  const int j    = blockIdx.y;   // original joint
  const int b    = blockIdx.z;   // batch
  const int tid  = (int)threadIdx.x;
  const int lane = tid & 63;
  // wave id, forced into an SGPR so all W/bias/out-channel indexing is
  // provably uniform -> scalar loads on the (idle) scalar pipe, no LDS.
  const int wv  = __builtin_amdgcn_readfirstlane(tid >> 6);
  const int co0 = wv * 4;       // this wave handles co0..co0+3

  const int t0 = tile * TILE_T + lane * 4;

  // acc[cc] for co = co0+cc, initialized with bias (uniform scalar loads)
  float4 acc[4];
#pragma unroll
  for (int cc = 0; cc < 4; ++cc) {
    const float bb = bias[co0 + cc];
    acc[cc] = make_float4(bb, bb, bb, bb);
  }

  // Weight base for this wave's co-group: W[(co*NCI + ci)*3 + k]
  const float* __restrict__ Wg = W + (size_t)co0 * NCI * 3;

#pragma unroll 4
  for (int ci = 0; ci < NCI; ++ci) {
    const float* xp = x + (((size_t)b * NCI + ci) * J_DIM + j) * T_DIM;
    const float4 v = *(const float4*)(xp + t0);
    // t-halo via in-wave shuffle; wave-edge lanes patch with a direct load
    float xm1 = __shfl_up(v.w, 1);
    float xp4 = __shfl_down(v.x, 1);
    if (lane == 0)  xm1 = (t0 > 0) ? xp[t0 - 1] : 0.f;
    if (lane == 63) xp4 = (t0 + 4 < T_DIM) ? xp[t0 + 4] : 0.f;

#pragma unroll
    for (int cc = 0; cc < 4; ++cc) {
      // uniform indices -> s_load (SGPR operands in the FMAs below)
      const float w0 = Wg[(cc * NCI + ci) * 3 + 0];
      const float w1 = Wg[(cc * NCI + ci) * 3 + 1];
      const float w2 = Wg[(cc * NCI + ci) * 3 + 2];
      acc[cc].x = fmaf(xm1, w0, fmaf(v.x, w1, fmaf(v.y, w2, acc[cc].x)));
      acc[cc].y = fmaf(v.x, w0, fmaf(v.y, w1, fmaf(v.z, w2, acc[cc].y)));
      acc[cc].z = fmaf(v.y, w0, fmaf(v.z, w1, fmaf(v.w, w2, acc[cc].z)));
      acc[cc].w = fmaf(v.z, w0, fmaf(v.w, w1, fmaf(xp4, w2, acc[cc].w)));
    }
  }

  // replicate this joint's conv result to all its gather positions
  const int nrep = d_nrep[j];
  for (int r = 0; r < nrep; ++r) {
    const int g = d_repl[j][r];
    float* op = out + (((size_t)b * NCO + co0) * G_DIM + g) * T_DIM + t0;
#pragma unroll
    for (int cc = 0; cc < 4; ++cc) {
      *(float4*)(op + (size_t)cc * (G_DIM * T_DIM)) = acc[cc];
    }
  }
}

extern "C" void kernel_launch(void* const* d_in, const int* in_sizes, int n_in,
                              void* d_out, int out_size, void* d_ws, size_t ws_size,
                              hipStream_t stream) {
  const float* x    = (const float*)d_in[0];
  const float* W    = (const float*)d_in[1];
  const float* bias = (const float*)d_in[2];
  float* out = (float*)d_out;

  dim3 grid(T_DIM / TILE_T, J_DIM, 32);  // 16 x 24 x 32 = 12288 blocks
  dim3 block(256);
  skel_conv<<<grid, block, 0, stream>>>(x, W, bias, out);
}